// Round 4
// baseline (586.055 us; speedup 1.0000x reference)
//
#include <hip/hip_runtime.h>
#include <hip/hip_bf16.h>
#include <stdint.h>

// Problem: N=512, S=256, D=512, C=1024, CLASSES=1000 (all fp32 in/out)
// d_out = [logits 512x1000][recon 512x512][ew 512x256] fp32 flat.
// d_ws layout: [0,1MB): codebook bf16 (pre-scaled by 1/sqrt(D)), natural [c][k]
//              [1MB,3MB): cw fp32 [512][1024]
//              [3MB,4MB): summary fp32 [512][512]

typedef float  f32x4 __attribute__((ext_vector_type(4)));
typedef float  f32x2 __attribute__((ext_vector_type(2)));
typedef short  s16x8 __attribute__((ext_vector_type(8)));

__device__ __forceinline__ unsigned short f2bf(float x){
  unsigned u = __float_as_uint(x);
  u += 0x7fffu + ((u >> 16) & 1u);           // RNE
  return (unsigned short)(u >> 16);
}
__device__ __forceinline__ float hsum4(f32x4 v){ return v[0]+v[1]+v[2]+v[3]; }

static constexpr float INV_SCALE = 0.04419417382415922f; // 1/sqrt(512)

// ---------------------------------------------------------------------------
// Kernel A0: codebook fp32 -> bf16 * (1/sqrt(D)), natural [c=1024][k=512].
// ---------------------------------------------------------------------------
__global__ __launch_bounds__(256) void k_cbarr(const float* __restrict__ cb,
                                               unsigned short* __restrict__ cbB){
  const int g = blockIdx.x*256 + threadIdx.x;   // 0..65535, 8 elems each
  const float* src = cb + (size_t)g*8;
  const f32x4 v0 = *(const f32x4*)(src);
  const f32x4 v1 = *(const f32x4*)(src + 4);
  s16x8 o;
  o[0]=(short)f2bf(v0[0]*INV_SCALE); o[1]=(short)f2bf(v0[1]*INV_SCALE);
  o[2]=(short)f2bf(v0[2]*INV_SCALE); o[3]=(short)f2bf(v0[3]*INV_SCALE);
  o[4]=(short)f2bf(v1[0]*INV_SCALE); o[5]=(short)f2bf(v1[1]*INV_SCALE);
  o[6]=(short)f2bf(v1[2]*INV_SCALE); o[7]=(short)f2bf(v1[3]*INV_SCALE);
  *(s16x8*)(cbB + (size_t)g*8) = o;
}

// ---------------------------------------------------------------------------
// Kernel A1: q_proj = q@Wq^T; cw = softmax(q_proj@cb^T/sqrt(D)). 4 n per block.
// ---------------------------------------------------------------------------
__global__ __launch_bounds__(256) void k_cw(const float* __restrict__ q,
                                            const float* __restrict__ Wq,
                                            const float* __restrict__ cb,
                                            float* __restrict__ cw){
  __shared__ __align__(16) float qrow[4][512];
  __shared__ __align__(16) float qproj[4][512];
  __shared__ float ev[4][1024];
  __shared__ float red[256];
  __shared__ float tot[4];
  const int t = threadIdx.x;
  const int n0 = blockIdx.x*4;

  #pragma unroll
  for (int j = 0; j < 8; ++j){
    const int o = t + 256*j; const int ni = o >> 9, d = o & 511;
    qrow[ni][d] = q[(size_t)(n0+ni)*512 + d];
  }
  __syncthreads();

  {
    const f32x4* q0 = (const f32x4*)qrow[0];
    const f32x4* q1 = (const f32x4*)qrow[1];
    const f32x4* q2 = (const f32x4*)qrow[2];
    const f32x4* q3 = (const f32x4*)qrow[3];
    #pragma unroll 1
    for (int j = 0; j < 2; ++j){
      const int e = t + 256*j;
      const f32x4* w4 = (const f32x4*)(Wq + (size_t)e*512);
      f32x4 a0={0,0,0,0},a1={0,0,0,0},a2={0,0,0,0},a3={0,0,0,0};
      for (int d = 0; d < 128; ++d){
        const f32x4 wv = w4[d];
        a0 += wv*q0[d]; a1 += wv*q1[d]; a2 += wv*q2[d]; a3 += wv*q3[d];
      }
      qproj[0][e]=hsum4(a0); qproj[1][e]=hsum4(a1); qproj[2][e]=hsum4(a2); qproj[3][e]=hsum4(a3);
    }
  }
  __syncthreads();

  {
    const f32x4* p0 = (const f32x4*)qproj[0];
    const f32x4* p1 = (const f32x4*)qproj[1];
    const f32x4* p2 = (const f32x4*)qproj[2];
    const f32x4* p3 = (const f32x4*)qproj[3];
    #pragma unroll 1
    for (int j = 0; j < 4; ++j){
      const int c = t + 256*j;
      const f32x4* c4 = (const f32x4*)(cb + (size_t)c*512);
      f32x4 a0={0,0,0,0},a1={0,0,0,0},a2={0,0,0,0},a3={0,0,0,0};
      for (int d = 0; d < 128; ++d){
        const f32x4 wv = c4[d];
        a0 += wv*p0[d]; a1 += wv*p1[d]; a2 += wv*p2[d]; a3 += wv*p3[d];
      }
      ev[0][c] = __expf(hsum4(a0)*INV_SCALE);
      ev[1][c] = __expf(hsum4(a1)*INV_SCALE);
      ev[2][c] = __expf(hsum4(a2)*INV_SCALE);
      ev[3][c] = __expf(hsum4(a3)*INV_SCALE);
    }
  }
  __syncthreads();

  for (int ni = 0; ni < 4; ++ni){
    red[t] = ev[ni][t] + ev[ni][t+256] + ev[ni][t+512] + ev[ni][t+768];
    __syncthreads();
    for (int off = 128; off > 0; off >>= 1){
      if (t < off) red[t] += red[t+off];
      __syncthreads();
    }
    if (t == 0) tot[ni] = red[0];
    __syncthreads();
  }
  #pragma unroll
  for (int j = 0; j < 16; ++j){
    const int o = t + 256*j; const int ni = o >> 10, c = o & 1023;
    cw[(size_t)(n0+ni)*1024 + c] = ev[ni][c] / tot[ni];
  }
}

// ---------------------------------------------------------------------------
// Kernel B: per block 64 rows (one n) x all 1024 c. A-tile in LDS
// (XOR-swizzled); B direct L2->VGPR. Explicit software pipeline, fully
// unrolled: b[2][4] ping-pong prefetched 2 kk ahead, a[] issued 1 kk ahead,
// counted s_waitcnt vmcnt(4)/lgkmcnt(0), sched_barrier fences, setprio
// around the 16-MFMA cluster. LDS 72 KB -> 2 blocks/CU, 4 waves/SIMD.
// ---------------------------------------------------------------------------
__global__ __launch_bounds__(512, 4) void k_scores(const float* __restrict__ Kt,
                                                   const unsigned short* __restrict__ cbB,
                                                   const float* __restrict__ cw,
                                                   float* __restrict__ ew_out){
  __shared__ __align__(16) short sA[64*512];      // 64 KB
  __shared__ float cwl[1024];                     // 4 KB
  __shared__ float pe[8][64];                     // 2 KB
  __shared__ float pw[8][64];                     // 2 KB

  const int t    = threadIdx.x;
  const int lane = t & 63;
  const int w    = t >> 6;
  const int m0   = blockIdx.x * 64;   // row base (n*256+s); 64|256 -> one n
  const int n    = m0 >> 8;

  // ---- stage A tile: fp32 -> bf16 (RNE), slot ^= (row&7) swizzle ----
  {
    const int row = t >> 3;
    const float* src = Kt + (size_t)(m0 + row) * 512;
    #pragma unroll
    for (int j = 0; j < 8; ++j){
      const int slot = (t & 7) + 8*j;
      const f32x4 v0 = *(const f32x4*)(src + slot*8);
      const f32x4 v1 = *(const f32x4*)(src + slot*8 + 4);
      s16x8 o;
      o[0]=(short)f2bf(v0[0]); o[1]=(short)f2bf(v0[1]); o[2]=(short)f2bf(v0[2]); o[3]=(short)f2bf(v0[3]);
      o[4]=(short)f2bf(v1[0]); o[5]=(short)f2bf(v1[1]); o[6]=(short)f2bf(v1[2]); o[7]=(short)f2bf(v1[3]);
      const int sp = slot ^ (row & 7);
      *(s16x8*)&sA[row*512 + sp*8] = o;
    }
  }
  cwl[t]       = cw[(size_t)n*1024 + t];
  cwl[t + 512] = cw[(size_t)n*1024 + t + 512];
  pe[w][lane] = 0.f;
  pw[w][lane] = 0.f;
  __syncthreads();

  const int kg = lane >> 4;
  const int lr = lane & 15;

  #pragma unroll 1
  for (int ci = 0; ci < 2; ++ci){
    f32x4 acc[4][4];
    #pragma unroll
    for (int fr = 0; fr < 4; ++fr)
      #pragma unroll
      for (int fc = 0; fc < 4; ++fc) acc[fr][fc] = (f32x4){0.f,0.f,0.f,0.f};

    // B: crow = ci*512 + w*64 + fc*16 + lr; bytes = crow*1024 + kk*64 + kg*16
    const unsigned short* bptr = cbB + ((size_t)(ci*512 + w*64 + lr))*512 + kg*8;

    s16x8 a[4], b[2][4];
    // ---- prologue: B(0), B(1), A(0) ----
    #pragma unroll
    for (int fc = 0; fc < 4; ++fc)
      b[0][fc] = *(const s16x8*)(bptr + fc*8192 + 0*32);
    #pragma unroll
    for (int fc = 0; fc < 4; ++fc)
      b[1][fc] = *(const s16x8*)(bptr + fc*8192 + 1*32);
    #pragma unroll
    for (int fr = 0; fr < 4; ++fr){
      const int row = fr*16 + lr;
      const int sp  = (0*4 + kg) ^ (row & 7);
      a[fr] = *(const s16x8*)&sA[row*512 + sp*8];
    }

    #pragma unroll
    for (int kk = 0; kk < 16; ++kk){
      if (kk < 15) asm volatile("s_waitcnt vmcnt(4) lgkmcnt(0)" ::: "memory");
      else         asm volatile("s_waitcnt vmcnt(0) lgkmcnt(0)" ::: "memory");
      __builtin_amdgcn_sched_barrier(0);
      __builtin_amdgcn_s_setprio(1);
      #pragma unroll
      for (int fr = 0; fr < 4; ++fr)
        #pragma unroll
        for (int fc = 0; fc < 4; ++fc)
          acc[fr][fc] = __builtin_amdgcn_mfma_f32_16x16x32_bf16(a[fr], b[kk & 1][fc], acc[fr][fc], 0, 0, 0);
      __builtin_amdgcn_s_setprio(0);
      __builtin_amdgcn_sched_barrier(0);
      if (kk < 15){
        #pragma unroll
        for (int fr = 0; fr < 4; ++fr){
          const int row = fr*16 + lr;
          const int sp  = ((kk+1)*4 + kg) ^ (row & 7);
          a[fr] = *(const s16x8*)&sA[row*512 + sp*8];
        }
      }
      if (kk < 14){
        #pragma unroll
        for (int fc = 0; fc < 4; ++fc)
          b[kk & 1][fc] = *(const s16x8*)(bptr + fc*8192 + (kk+2)*32);
      }
    }

    // per-ci epilogue: exp + cw-weight + 16-lane shuffle reduction into pe/pw
    #pragma unroll
    for (int fr = 0; fr < 4; ++fr){
      float es[4] = {0,0,0,0}, ws[4] = {0,0,0,0};
      #pragma unroll
      for (int fc = 0; fc < 4; ++fc){
        const int c = ci*512 + w*64 + fc*16 + lr;
        const float cwv = cwl[c];
        #pragma unroll
        for (int r = 0; r < 4; ++r){
          const float e = __expf(acc[fr][fc][r]);   // scale pre-folded into cb
          es[r] += e;
          ws[r] += e * cwv;
        }
      }
      #pragma unroll
      for (int r = 0; r < 4; ++r){
        float a0 = es[r], b0 = ws[r];
        #pragma unroll
        for (int m = 1; m < 16; m <<= 1){
          a0 += __shfl_xor(a0, m, 64);
          b0 += __shfl_xor(b0, m, 64);
        }
        if (lr == 0){
          const int row = fr*16 + kg*4 + r;   // C/D map: row=(l>>4)*4+reg
          pe[w][row] += a0;
          pw[w][row] += b0;
        }
      }
    }
  }

  __syncthreads();
  if (t < 64){
    float se = 0.f, sw = 0.f;
    #pragma unroll
    for (int i = 0; i < 8; ++i){ se += pe[i][t]; sw += pw[i][t]; }
    ew_out[m0 + t] = sw / se;
  }
}

// ---------------------------------------------------------------------------
// Kernel C: summary[n][d] = sum_s ew[n,s] * V[n,s,d]. grid = n x d-half.
// ---------------------------------------------------------------------------
__global__ __launch_bounds__(256) void k_summary(const float* __restrict__ V,
                                                 const float* __restrict__ ew,
                                                 float* __restrict__ sm){
  __shared__ float e[256];
  __shared__ f32x4 red[3][64];
  const int t = threadIdx.x;
  const int lane = t & 63, w = t >> 6;
  const int n = blockIdx.x >> 1;
  const int d0 = (blockIdx.x & 1) * 256;
  e[t] = ew[(size_t)n*256 + t];
  __syncthreads();
  const float* vb = V + (size_t)n*131072 + d0 + lane*4;
  f32x4 acc = {0.f,0.f,0.f,0.f};
  #pragma unroll 8
  for (int s = w; s < 256; s += 4){
    const f32x4 v = *(const f32x4*)(vb + (size_t)s*512);
    acc += e[s] * v;
  }
  if (w > 0) red[w-1][lane] = acc;
  __syncthreads();
  if (w == 0){
    acc += red[0][lane] + red[1][lane] + red[2][lane];
    *(f32x4*)(sm + (size_t)n*512 + d0 + lane*4) = acc;
  }
}

// ---------------------------------------------------------------------------
// Kernel D: logits = sm@Wc^T + bc ; recon = sm@Wr^T + br. 4 n per block.
// ---------------------------------------------------------------------------
__global__ __launch_bounds__(256) void k_readout(const float* __restrict__ sm,
                                                 const float* __restrict__ Wc,
                                                 const float* __restrict__ bc,
                                                 const float* __restrict__ Wr,
                                                 const float* __restrict__ br,
                                                 float* __restrict__ logits,
                                                 float* __restrict__ recon){
  __shared__ __align__(16) float sl[4][512];
  const int t = threadIdx.x;
  const int n0 = blockIdx.x * 4;
  #pragma unroll
  for (int j = 0; j < 8; ++j){
    const int o = t + 256*j; const int ni = o >> 9, d = o & 511;
    sl[ni][d] = sm[(size_t)(n0+ni)*512 + d];
  }
  __syncthreads();
  const f32x4* s0 = (const f32x4*)sl[0];
  const f32x4* s1 = (const f32x4*)sl[1];
  const f32x4* s2 = (const f32x4*)sl[2];
  const f32x4* s3 = (const f32x4*)sl[3];
  #pragma unroll 1
  for (int j = 0; j < 6; ++j){
    const int o = t + 256*j;
    if (o >= 1512) continue;
    const bool isl = o < 1000;
    const float* wrow = isl ? (Wc + (size_t)o*512) : (Wr + (size_t)(o-1000)*512);
    const float bias  = isl ? bc[o] : br[o-1000];
    const f32x4* w4 = (const f32x4*)wrow;
    f32x4 a0={0,0,0,0},a1={0,0,0,0},a2={0,0,0,0},a3={0,0,0,0};
    for (int d = 0; d < 128; ++d){
      const f32x4 wv = w4[d];
      a0 += wv*s0[d]; a1 += wv*s1[d]; a2 += wv*s2[d]; a3 += wv*s3[d];
    }
    const float r0 = hsum4(a0) + bias;
    const float r1 = hsum4(a1) + bias;
    const float r2 = hsum4(a2) + bias;
    const float r3 = hsum4(a3) + bias;
    if (isl){
      logits[(size_t)(n0+0)*1000 + o] = r0;
      logits[(size_t)(n0+1)*1000 + o] = r1;
      logits[(size_t)(n0+2)*1000 + o] = r2;
      logits[(size_t)(n0+3)*1000 + o] = r3;
    } else {
      const int eI = o - 1000;
      recon[(size_t)(n0+0)*512 + eI] = r0;
      recon[(size_t)(n0+1)*512 + eI] = r1;
      recon[(size_t)(n0+2)*512 + eI] = r2;
      recon[(size_t)(n0+3)*512 + eI] = r3;
    }
  }
}

extern "C" void kernel_launch(void* const* d_in, const int* in_sizes, int n_in,
                              void* d_out, int out_size, void* d_ws, size_t ws_size,
                              hipStream_t stream) {
  const float* q  = (const float*)d_in[0];
  const float* K  = (const float*)d_in[1];
  const float* V  = (const float*)d_in[2];
  const float* cb = (const float*)d_in[3];
  const float* Wq = (const float*)d_in[4];
  const float* Wc = (const float*)d_in[5];
  const float* bc = (const float*)d_in[6];
  const float* Wr = (const float*)d_in[7];
  const float* br = (const float*)d_in[8];

  float* out    = (float*)d_out;
  float* logits = out;                         // 512*1000
  float* recon  = out + 512*1000;              // 512*512
  float* ew     = out + 512*1000 + 512*512;    // 512*256

  char* wsb = (char*)d_ws;
  unsigned short* cbB = (unsigned short*)wsb;            // 1 MB
  float* cw = (float*)(wsb + (1u<<20));                  // 2 MB
  float* sm = (float*)(wsb + 3u*(1u<<20));               // 1 MB

  hipLaunchKernelGGL(k_cbarr,   dim3(256),  dim3(256), 0, stream, cb, cbB);
  hipLaunchKernelGGL(k_cw,      dim3(128),  dim3(256), 0, stream, q, Wq, cb, cw);
  hipLaunchKernelGGL(k_scores,  dim3(2048), dim3(512), 0, stream, K, cbB, cw, ew);
  hipLaunchKernelGGL(k_summary, dim3(1024), dim3(256), 0, stream, V, ew, sm);
  hipLaunchKernelGGL(k_readout, dim3(128),  dim3(256), 0, stream, sm, Wc, bc, Wr, br, logits, recon);
}

// Round 5
// 515.346 us; speedup vs baseline: 1.1372x; 1.1372x over previous
//
#include <hip/hip_runtime.h>
#include <hip/hip_bf16.h>
#include <stdint.h>

// Problem: N=512, S=256, D=512, C=1024, CLASSES=1000 (all fp32 in/out)
// d_out = [logits 512x1000][recon 512x512][ew 512x256] fp32 flat.
// d_ws layout: [0,1MB): codebook bf16 (pre-scaled by 1/sqrt(D)), panel-chunk-major
//              [1MB,3MB): cw fp32 [512][1024]
//              [3MB,4MB): summary fp32 [512][512]

typedef float  f32x4 __attribute__((ext_vector_type(4)));
typedef float  f32x2 __attribute__((ext_vector_type(2)));
typedef short  s16x8 __attribute__((ext_vector_type(8)));

__device__ __forceinline__ unsigned short f2bf(float x){
  unsigned u = __float_as_uint(x);
  u += 0x7fffu + ((u >> 16) & 1u);           // RNE
  return (unsigned short)(u >> 16);
}
__device__ __forceinline__ float hsum4(f32x4 v){ return v[0]+v[1]+v[2]+v[3]; }

static constexpr float INV_SCALE = 0.04419417382415922f; // 1/sqrt(512)

// ---------------------------------------------------------------------------
// Kernel A0: codebook fp32 -> bf16 * (1/sqrt(D)), PANEL-CHUNK-MAJOR layout:
// elem index = (((ci*8+w)*16 + kk)*64 + cr)*32 + ks
// where c = ci*512 + w*64 + cr, k = kk*32 + ks.
// -> each (wave panel, kk) chunk is 4 KB contiguous; a wave's per-kk fragment
// load (fc,lr,kg) is 64 lanes x 16 B fully coalesced.
// ---------------------------------------------------------------------------
__global__ __launch_bounds__(256) void k_cbarr(const float* __restrict__ cb,
                                               unsigned short* __restrict__ cbB){
  const int g = blockIdx.x*256 + threadIdx.x;   // 0..65535, 8 elems each
  const int ks8 = g & 3;            // k sub-block of 8
  const int cr  = (g >> 2) & 63;
  const int kk  = (g >> 8) & 15;
  const int wp  = (g >> 12) & 7;
  const int ci  = g >> 15;
  const int c = ci*512 + wp*64 + cr;
  const int k = kk*32 + ks8*8;
  const float* src = cb + (size_t)c*512 + k;
  const f32x4 v0 = *(const f32x4*)(src);
  const f32x4 v1 = *(const f32x4*)(src + 4);
  s16x8 o;
  o[0]=(short)f2bf(v0[0]*INV_SCALE); o[1]=(short)f2bf(v0[1]*INV_SCALE);
  o[2]=(short)f2bf(v0[2]*INV_SCALE); o[3]=(short)f2bf(v0[3]*INV_SCALE);
  o[4]=(short)f2bf(v1[0]*INV_SCALE); o[5]=(short)f2bf(v1[1]*INV_SCALE);
  o[6]=(short)f2bf(v1[2]*INV_SCALE); o[7]=(short)f2bf(v1[3]*INV_SCALE);
  *(s16x8*)(cbB + (size_t)g*8) = o;
}

// ---------------------------------------------------------------------------
// Kernel A1: q_proj = q@Wq^T; cw = softmax(q_proj@cb^T/sqrt(D)). 4 n per block.
// ---------------------------------------------------------------------------
__global__ __launch_bounds__(256) void k_cw(const float* __restrict__ q,
                                            const float* __restrict__ Wq,
                                            const float* __restrict__ cb,
                                            float* __restrict__ cw){
  __shared__ __align__(16) float qrow[4][512];
  __shared__ __align__(16) float qproj[4][512];
  __shared__ float ev[4][1024];
  __shared__ float red[256];
  __shared__ float tot[4];
  const int t = threadIdx.x;
  const int n0 = blockIdx.x*4;

  #pragma unroll
  for (int j = 0; j < 8; ++j){
    const int o = t + 256*j; const int ni = o >> 9, d = o & 511;
    qrow[ni][d] = q[(size_t)(n0+ni)*512 + d];
  }
  __syncthreads();

  {
    const f32x4* q0 = (const f32x4*)qrow[0];
    const f32x4* q1 = (const f32x4*)qrow[1];
    const f32x4* q2 = (const f32x4*)qrow[2];
    const f32x4* q3 = (const f32x4*)qrow[3];
    #pragma unroll 1
    for (int j = 0; j < 2; ++j){
      const int e = t + 256*j;
      const f32x4* w4 = (const f32x4*)(Wq + (size_t)e*512);
      f32x4 a0={0,0,0,0},a1={0,0,0,0},a2={0,0,0,0},a3={0,0,0,0};
      for (int d = 0; d < 128; ++d){
        const f32x4 wv = w4[d];
        a0 += wv*q0[d]; a1 += wv*q1[d]; a2 += wv*q2[d]; a3 += wv*q3[d];
      }
      qproj[0][e]=hsum4(a0); qproj[1][e]=hsum4(a1); qproj[2][e]=hsum4(a2); qproj[3][e]=hsum4(a3);
    }
  }
  __syncthreads();

  {
    const f32x4* p0 = (const f32x4*)qproj[0];
    const f32x4* p1 = (const f32x4*)qproj[1];
    const f32x4* p2 = (const f32x4*)qproj[2];
    const f32x4* p3 = (const f32x4*)qproj[3];
    #pragma unroll 1
    for (int j = 0; j < 4; ++j){
      const int c = t + 256*j;
      const f32x4* c4 = (const f32x4*)(cb + (size_t)c*512);
      f32x4 a0={0,0,0,0},a1={0,0,0,0},a2={0,0,0,0},a3={0,0,0,0};
      for (int d = 0; d < 128; ++d){
        const f32x4 wv = c4[d];
        a0 += wv*p0[d]; a1 += wv*p1[d]; a2 += wv*p2[d]; a3 += wv*p3[d];
      }
      ev[0][c] = __expf(hsum4(a0)*INV_SCALE);
      ev[1][c] = __expf(hsum4(a1)*INV_SCALE);
      ev[2][c] = __expf(hsum4(a2)*INV_SCALE);
      ev[3][c] = __expf(hsum4(a3)*INV_SCALE);
    }
  }
  __syncthreads();

  for (int ni = 0; ni < 4; ++ni){
    red[t] = ev[ni][t] + ev[ni][t+256] + ev[ni][t+512] + ev[ni][t+768];
    __syncthreads();
    for (int off = 128; off > 0; off >>= 1){
      if (t < off) red[t] += red[t+off];
      __syncthreads();
    }
    if (t == 0) tot[ni] = red[0];
    __syncthreads();
  }
  #pragma unroll
  for (int j = 0; j < 16; ++j){
    const int o = t + 256*j; const int ni = o >> 10, c = o & 1023;
    cw[(size_t)(n0+ni)*1024 + c] = ev[ni][c] / tot[ni];
  }
}

// ---------------------------------------------------------------------------
// Kernel B: per block 64 rows (one n) x all 1024 c. A-tile in LDS
// (XOR-swizzled); B direct L2->VGPR from panel-chunk-major cbB (coalesced
// 1 KB wave loads). Explicit pipeline: a[2] ping-pong issued 1 kk ahead
// BEFORE the MFMA cluster; b[2] ping-pong issued 2 kk ahead AFTER it.
// Counted s_waitcnt vmcnt(4) lgkmcnt(0) at iter top. launch_bounds(512,2)
// -> 256-reg cap, no spills (round-4 lesson: (512,4) spilled 86 MB).
// ---------------------------------------------------------------------------
__global__ __launch_bounds__(512, 2) void k_scores(const float* __restrict__ Kt,
                                                   const unsigned short* __restrict__ cbB,
                                                   const float* __restrict__ cw,
                                                   float* __restrict__ ew_out){
  __shared__ __align__(16) short sA[64*512];      // 64 KB
  __shared__ float cwl[1024];                     // 4 KB
  __shared__ float pe[8][64];                     // 2 KB
  __shared__ float pw[8][64];                     // 2 KB

  const int t    = threadIdx.x;
  const int lane = t & 63;
  const int w    = t >> 6;
  const int m0   = blockIdx.x * 64;   // row base (n*256+s); 64|256 -> one n
  const int n    = m0 >> 8;

  // ---- stage A tile: fp32 -> bf16 (RNE), slot ^= (row&7) swizzle ----
  {
    const int row = t >> 3;
    const float* src = Kt + (size_t)(m0 + row) * 512;
    #pragma unroll
    for (int j = 0; j < 8; ++j){
      const int slot = (t & 7) + 8*j;
      const f32x4 v0 = *(const f32x4*)(src + slot*8);
      const f32x4 v1 = *(const f32x4*)(src + slot*8 + 4);
      s16x8 o;
      o[0]=(short)f2bf(v0[0]); o[1]=(short)f2bf(v0[1]); o[2]=(short)f2bf(v0[2]); o[3]=(short)f2bf(v0[3]);
      o[4]=(short)f2bf(v1[0]); o[5]=(short)f2bf(v1[1]); o[6]=(short)f2bf(v1[2]); o[7]=(short)f2bf(v1[3]);
      const int sp = slot ^ (row & 7);
      *(s16x8*)&sA[row*512 + sp*8] = o;
    }
  }
  cwl[t]       = cw[(size_t)n*1024 + t];
  cwl[t + 512] = cw[(size_t)n*1024 + t + 512];
  pe[w][lane] = 0.f;
  pw[w][lane] = 0.f;
  __syncthreads();

  const int kg = lane >> 4;
  const int lr = lane & 15;

  #pragma unroll 1
  for (int ci = 0; ci < 2; ++ci){
    f32x4 acc[4][4];
    #pragma unroll
    for (int fr = 0; fr < 4; ++fr)
      #pragma unroll
      for (int fc = 0; fc < 4; ++fc) acc[fr][fc] = (f32x4){0.f,0.f,0.f,0.f};

    // panel base: chunks (ci*8+w)*16 + kk, each 2048 elems; lane offset
    // (fc*16+lr)*32 + kg*8 -> 64 lanes x 16 B contiguous per fc.
    const unsigned short* pbase = cbB + ((size_t)(ci*8 + w)*16)*2048;
    const int loff = lr*32 + kg*8;

    s16x8 a[2][4], b[2][4];
    // ---- prologue: B(0), B(1), A(0) ----
    #pragma unroll
    for (int fc = 0; fc < 4; ++fc)
      b[0][fc] = *(const s16x8*)(pbase + 0*2048 + fc*512 + loff);
    #pragma unroll
    for (int fc = 0; fc < 4; ++fc)
      b[1][fc] = *(const s16x8*)(pbase + 1*2048 + fc*512 + loff);
    #pragma unroll
    for (int fr = 0; fr < 4; ++fr){
      const int row = fr*16 + lr;
      const int sp  = (0*4 + kg) ^ (row & 7);
      a[0][fr] = *(const s16x8*)&sA[row*512 + sp*8];
    }

    #pragma unroll
    for (int kk = 0; kk < 16; ++kk){
      if (kk < 15) asm volatile("s_waitcnt vmcnt(4) lgkmcnt(0)" ::: "memory");
      else         asm volatile("s_waitcnt vmcnt(0) lgkmcnt(0)" ::: "memory");
      __builtin_amdgcn_sched_barrier(0);
      // A prefetch for kk+1 into alternate buffer (RAW-safe vs cluster kk)
      if (kk < 15){
        #pragma unroll
        for (int fr = 0; fr < 4; ++fr){
          const int row = fr*16 + lr;
          const int sp  = ((kk+1)*4 + kg) ^ (row & 7);
          a[(kk+1) & 1][fr] = *(const s16x8*)&sA[row*512 + sp*8];
        }
      }
      __builtin_amdgcn_sched_barrier(0);
      __builtin_amdgcn_s_setprio(1);
      #pragma unroll
      for (int fr = 0; fr < 4; ++fr)
        #pragma unroll
        for (int fc = 0; fc < 4; ++fc)
          acc[fr][fc] = __builtin_amdgcn_mfma_f32_16x16x32_bf16(a[kk & 1][fr], b[kk & 1][fc], acc[fr][fc], 0, 0, 0);
      __builtin_amdgcn_s_setprio(0);
      __builtin_amdgcn_sched_barrier(0);
      // B prefetch for kk+2 overwriting b[kk&1] (WAR-safe: cluster kk done)
      if (kk < 14){
        #pragma unroll
        for (int fc = 0; fc < 4; ++fc)
          b[kk & 1][fc] = *(const s16x8*)(pbase + (size_t)(kk+2)*2048 + fc*512 + loff);
      }
    }

    // per-ci epilogue: exp + cw-weight + 16-lane shuffle reduction into pe/pw
    #pragma unroll
    for (int fr = 0; fr < 4; ++fr){
      float es[4] = {0,0,0,0}, ws[4] = {0,0,0,0};
      #pragma unroll
      for (int fc = 0; fc < 4; ++fc){
        const int c = ci*512 + w*64 + fc*16 + lr;
        const float cwv = cwl[c];
        #pragma unroll
        for (int r = 0; r < 4; ++r){
          const float e = __expf(acc[fr][fc][r]);   // scale pre-folded into cb
          es[r] += e;
          ws[r] += e * cwv;
        }
      }
      #pragma unroll
      for (int r = 0; r < 4; ++r){
        float a0 = es[r], b0 = ws[r];
        #pragma unroll
        for (int m = 1; m < 16; m <<= 1){
          a0 += __shfl_xor(a0, m, 64);
          b0 += __shfl_xor(b0, m, 64);
        }
        if (lr == 0){
          const int row = fr*16 + kg*4 + r;   // C/D map: row=(l>>4)*4+reg
          pe[w][row] += a0;
          pw[w][row] += b0;
        }
      }
    }
  }

  __syncthreads();
  if (t < 64){
    float se = 0.f, sw = 0.f;
    #pragma unroll
    for (int i = 0; i < 8; ++i){ se += pe[i][t]; sw += pw[i][t]; }
    ew_out[m0 + t] = sw / se;
  }
}

// ---------------------------------------------------------------------------
// Kernel C: summary[n][d] = sum_s ew[n,s] * V[n,s,d]. grid = n x d-half.
// ---------------------------------------------------------------------------
__global__ __launch_bounds__(256) void k_summary(const float* __restrict__ V,
                                                 const float* __restrict__ ew,
                                                 float* __restrict__ sm){
  __shared__ float e[256];
  __shared__ f32x4 red[3][64];
  const int t = threadIdx.x;
  const int lane = t & 63, w = t >> 6;
  const int n = blockIdx.x >> 1;
  const int d0 = (blockIdx.x & 1) * 256;
  e[t] = ew[(size_t)n*256 + t];
  __syncthreads();
  const float* vb = V + (size_t)n*131072 + d0 + lane*4;
  f32x4 acc = {0.f,0.f,0.f,0.f};
  #pragma unroll 8
  for (int s = w; s < 256; s += 4){
    const f32x4 v = *(const f32x4*)(vb + (size_t)s*512);
    acc += e[s] * v;
  }
  if (w > 0) red[w-1][lane] = acc;
  __syncthreads();
  if (w == 0){
    acc += red[0][lane] + red[1][lane] + red[2][lane];
    *(f32x4*)(sm + (size_t)n*512 + d0 + lane*4) = acc;
  }
}

// ---------------------------------------------------------------------------
// Kernel D: logits = sm@Wc^T + bc ; recon = sm@Wr^T + br. 4 n per block.
// ---------------------------------------------------------------------------
__global__ __launch_bounds__(256) void k_readout(const float* __restrict__ sm,
                                                 const float* __restrict__ Wc,
                                                 const float* __restrict__ bc,
                                                 const float* __restrict__ Wr,
                                                 const float* __restrict__ br,
                                                 float* __restrict__ logits,
                                                 float* __restrict__ recon){
  __shared__ __align__(16) float sl[4][512];
  const int t = threadIdx.x;
  const int n0 = blockIdx.x * 4;
  #pragma unroll
  for (int j = 0; j < 8; ++j){
    const int o = t + 256*j; const int ni = o >> 9, d = o & 511;
    sl[ni][d] = sm[(size_t)(n0+ni)*512 + d];
  }
  __syncthreads();
  const f32x4* s0 = (const f32x4*)sl[0];
  const f32x4* s1 = (const f32x4*)sl[1];
  const f32x4* s2 = (const f32x4*)sl[2];
  const f32x4* s3 = (const f32x4*)sl[3];
  #pragma unroll 1
  for (int j = 0; j < 6; ++j){
    const int o = t + 256*j;
    if (o >= 1512) continue;
    const bool isl = o < 1000;
    const float* wrow = isl ? (Wc + (size_t)o*512) : (Wr + (size_t)(o-1000)*512);
    const float bias  = isl ? bc[o] : br[o-1000];
    const f32x4* w4 = (const f32x4*)wrow;
    f32x4 a0={0,0,0,0},a1={0,0,0,0},a2={0,0,0,0},a3={0,0,0,0};
    for (int d = 0; d < 128; ++d){
      const f32x4 wv = w4[d];
      a0 += wv*s0[d]; a1 += wv*s1[d]; a2 += wv*s2[d]; a3 += wv*s3[d];
    }
    const float r0 = hsum4(a0) + bias;
    const float r1 = hsum4(a1) + bias;
    const float r2 = hsum4(a2) + bias;
    const float r3 = hsum4(a3) + bias;
    if (isl){
      logits[(size_t)(n0+0)*1000 + o] = r0;
      logits[(size_t)(n0+1)*1000 + o] = r1;
      logits[(size_t)(n0+2)*1000 + o] = r2;
      logits[(size_t)(n0+3)*1000 + o] = r3;
    } else {
      const int eI = o - 1000;
      recon[(size_t)(n0+0)*512 + eI] = r0;
      recon[(size_t)(n0+1)*512 + eI] = r1;
      recon[(size_t)(n0+2)*512 + eI] = r2;
      recon[(size_t)(n0+3)*512 + eI] = r3;
    }
  }
}

extern "C" void kernel_launch(void* const* d_in, const int* in_sizes, int n_in,
                              void* d_out, int out_size, void* d_ws, size_t ws_size,
                              hipStream_t stream) {
  const float* q  = (const float*)d_in[0];
  const float* K  = (const float*)d_in[1];
  const float* V  = (const float*)d_in[2];
  const float* cb = (const float*)d_in[3];
  const float* Wq = (const float*)d_in[4];
  const float* Wc = (const float*)d_in[5];
  const float* bc = (const float*)d_in[6];
  const float* Wr = (const float*)d_in[7];
  const float* br = (const float*)d_in[8];

  float* out    = (float*)d_out;
  float* logits = out;                         // 512*1000
  float* recon  = out + 512*1000;              // 512*512
  float* ew     = out + 512*1000 + 512*512;    // 512*256

  char* wsb = (char*)d_ws;
  unsigned short* cbB = (unsigned short*)wsb;            // 1 MB
  float* cw = (float*)(wsb + (1u<<20));                  // 2 MB
  float* sm = (float*)(wsb + 3u*(1u<<20));               // 1 MB

  hipLaunchKernelGGL(k_cbarr,   dim3(256),  dim3(256), 0, stream, cb, cbB);
  hipLaunchKernelGGL(k_cw,      dim3(128),  dim3(256), 0, stream, q, Wq, cb, cw);
  hipLaunchKernelGGL(k_scores,  dim3(2048), dim3(512), 0, stream, K, cbB, cw, ew);
  hipLaunchKernelGGL(k_summary, dim3(1024), dim3(256), 0, stream, V, ew, sm);
  hipLaunchKernelGGL(k_readout, dim3(128),  dim3(256), 0, stream, sm, Wc, bc, Wr, br, logits, recon);
}

// Round 6
// 403.180 us; speedup vs baseline: 1.4536x; 1.2782x over previous
//
#include <hip/hip_runtime.h>
#include <hip/hip_bf16.h>
#include <stdint.h>

// Problem: N=512, S=256, D=512, C=1024, CLASSES=1000 (all fp32 in/out)
// d_out = [logits 512x1000][recon 512x512][ew 512x256] fp32 flat.
// d_ws layout: [0,1MB): codebook bf16 (pre-scaled by 1/sqrt(D)), 32c-panel-major
//              [1MB,3MB): cw fp32 [512][1024]
//              [3MB,4MB): summary fp32 [512][512]

typedef float  f32x4 __attribute__((ext_vector_type(4)));
typedef float  f32x2 __attribute__((ext_vector_type(2)));
typedef short  s16x8 __attribute__((ext_vector_type(8)));

__device__ __forceinline__ unsigned short f2bf(float x){
  unsigned u = __float_as_uint(x);
  u += 0x7fffu + ((u >> 16) & 1u);           // RNE
  return (unsigned short)(u >> 16);
}
__device__ __forceinline__ float hsum4(f32x4 v){ return v[0]+v[1]+v[2]+v[3]; }

static constexpr float INV_SCALE = 0.04419417382415922f; // 1/sqrt(512)

// ---------------------------------------------------------------------------
// Kernel A0: codebook fp32 -> bf16 * (1/sqrt(D)), 32c-PANEL-MAJOR layout:
// elem = ((p*16 + kk)*32 + cr)*32 + ks   with c = p*32+cr, k = kk*32+ks.
// A wave's per-kk fragment load (fc,lr,kg) is 2 x 1KB fully contiguous.
// ---------------------------------------------------------------------------
__global__ __launch_bounds__(256) void k_cbarr(const float* __restrict__ cb,
                                               unsigned short* __restrict__ cbB){
  const int g = blockIdx.x*256 + threadIdx.x;   // 0..65535, 8 elems each
  const int ks8 = g & 3;
  const int cr  = (g >> 2) & 31;
  const int kk  = (g >> 7) & 15;
  const int p   = g >> 11;                      // 0..31
  const int c = p*32 + cr;
  const int k = kk*32 + ks8*8;
  const float* src = cb + (size_t)c*512 + k;
  const f32x4 v0 = *(const f32x4*)(src);
  const f32x4 v1 = *(const f32x4*)(src + 4);
  s16x8 o;
  o[0]=(short)f2bf(v0[0]*INV_SCALE); o[1]=(short)f2bf(v0[1]*INV_SCALE);
  o[2]=(short)f2bf(v0[2]*INV_SCALE); o[3]=(short)f2bf(v0[3]*INV_SCALE);
  o[4]=(short)f2bf(v1[0]*INV_SCALE); o[5]=(short)f2bf(v1[1]*INV_SCALE);
  o[6]=(short)f2bf(v1[2]*INV_SCALE); o[7]=(short)f2bf(v1[3]*INV_SCALE);
  *(s16x8*)(cbB + (size_t)g*8) = o;
}

// ---------------------------------------------------------------------------
// Kernel A1: q_proj = q@Wq^T; cw = softmax(q_proj@cb^T/sqrt(D)). 4 n per block.
// ---------------------------------------------------------------------------
__global__ __launch_bounds__(256) void k_cw(const float* __restrict__ q,
                                            const float* __restrict__ Wq,
                                            const float* __restrict__ cb,
                                            float* __restrict__ cw){
  __shared__ __align__(16) float qrow[4][512];
  __shared__ __align__(16) float qproj[4][512];
  __shared__ float ev[4][1024];
  __shared__ float red[256];
  __shared__ float tot[4];
  const int t = threadIdx.x;
  const int n0 = blockIdx.x*4;

  #pragma unroll
  for (int j = 0; j < 8; ++j){
    const int o = t + 256*j; const int ni = o >> 9, d = o & 511;
    qrow[ni][d] = q[(size_t)(n0+ni)*512 + d];
  }
  __syncthreads();

  {
    const f32x4* q0 = (const f32x4*)qrow[0];
    const f32x4* q1 = (const f32x4*)qrow[1];
    const f32x4* q2 = (const f32x4*)qrow[2];
    const f32x4* q3 = (const f32x4*)qrow[3];
    #pragma unroll 1
    for (int j = 0; j < 2; ++j){
      const int e = t + 256*j;
      const f32x4* w4 = (const f32x4*)(Wq + (size_t)e*512);
      f32x4 a0={0,0,0,0},a1={0,0,0,0},a2={0,0,0,0},a3={0,0,0,0};
      for (int d = 0; d < 128; ++d){
        const f32x4 wv = w4[d];
        a0 += wv*q0[d]; a1 += wv*q1[d]; a2 += wv*q2[d]; a3 += wv*q3[d];
      }
      qproj[0][e]=hsum4(a0); qproj[1][e]=hsum4(a1); qproj[2][e]=hsum4(a2); qproj[3][e]=hsum4(a3);
    }
  }
  __syncthreads();

  {
    const f32x4* p0 = (const f32x4*)qproj[0];
    const f32x4* p1 = (const f32x4*)qproj[1];
    const f32x4* p2 = (const f32x4*)qproj[2];
    const f32x4* p3 = (const f32x4*)qproj[3];
    #pragma unroll 1
    for (int j = 0; j < 4; ++j){
      const int c = t + 256*j;
      const f32x4* c4 = (const f32x4*)(cb + (size_t)c*512);
      f32x4 a0={0,0,0,0},a1={0,0,0,0},a2={0,0,0,0},a3={0,0,0,0};
      for (int d = 0; d < 128; ++d){
        const f32x4 wv = c4[d];
        a0 += wv*p0[d]; a1 += wv*p1[d]; a2 += wv*p2[d]; a3 += wv*p3[d];
      }
      ev[0][c] = __expf(hsum4(a0)*INV_SCALE);
      ev[1][c] = __expf(hsum4(a1)*INV_SCALE);
      ev[2][c] = __expf(hsum4(a2)*INV_SCALE);
      ev[3][c] = __expf(hsum4(a3)*INV_SCALE);
    }
  }
  __syncthreads();

  for (int ni = 0; ni < 4; ++ni){
    red[t] = ev[ni][t] + ev[ni][t+256] + ev[ni][t+512] + ev[ni][t+768];
    __syncthreads();
    for (int off = 128; off > 0; off >>= 1){
      if (t < off) red[t] += red[t+off];
      __syncthreads();
    }
    if (t == 0) tot[ni] = red[0];
    __syncthreads();
  }
  #pragma unroll
  for (int j = 0; j < 16; ++j){
    const int o = t + 256*j; const int ni = o >> 10, c = o & 1023;
    cw[(size_t)(n0+ni)*1024 + c] = ev[ni][c] / tot[ni];
  }
}

// ---------------------------------------------------------------------------
// Kernel B: per block 64 rows (one n) x all 1024 c. A-tile in LDS
// (XOR-swizzled); B direct L2->VGPR from 32c-panel cbB. Wave tile 64x32 c,
// 4 c-passes. Registers sized for launch_bounds(512,4) without spill:
// acc[4][2]=32 + a[4]=16 + b[2][2]=16 + temps (<128 total incl AGPR).
// -> 2 blocks/CU, 4 waves/SIMD (TLP) + 2-deep B pipeline (ILP), vmcnt(2).
// ---------------------------------------------------------------------------
__global__ __launch_bounds__(512, 4) void k_scores(const float* __restrict__ Kt,
                                                   const unsigned short* __restrict__ cbB,
                                                   const float* __restrict__ cw,
                                                   float* __restrict__ ew_out){
  __shared__ __align__(16) short sA[64*512];      // 64 KB
  __shared__ float cwl[1024];                     // 4 KB
  __shared__ float pe[8][64];                     // 2 KB
  __shared__ float pw[8][64];                     // 2 KB

  const int t    = threadIdx.x;
  const int lane = t & 63;
  const int w    = t >> 6;
  const int m0   = blockIdx.x * 64;   // row base (n*256+s); 64|256 -> one n
  const int n    = m0 >> 8;

  // ---- stage A tile: fp32 -> bf16 (RNE), slot ^= (row&7) swizzle ----
  {
    const int row = t >> 3;
    const float* src = Kt + (size_t)(m0 + row) * 512;
    #pragma unroll
    for (int j = 0; j < 8; ++j){
      const int slot = (t & 7) + 8*j;
      const f32x4 v0 = *(const f32x4*)(src + slot*8);
      const f32x4 v1 = *(const f32x4*)(src + slot*8 + 4);
      s16x8 o;
      o[0]=(short)f2bf(v0[0]); o[1]=(short)f2bf(v0[1]); o[2]=(short)f2bf(v0[2]); o[3]=(short)f2bf(v0[3]);
      o[4]=(short)f2bf(v1[0]); o[5]=(short)f2bf(v1[1]); o[6]=(short)f2bf(v1[2]); o[7]=(short)f2bf(v1[3]);
      const int sp = slot ^ (row & 7);
      *(s16x8*)&sA[row*512 + sp*8] = o;
    }
  }
  cwl[t]       = cw[(size_t)n*1024 + t];
  cwl[t + 512] = cw[(size_t)n*1024 + t + 512];
  pe[w][lane] = 0.f;
  pw[w][lane] = 0.f;
  __syncthreads();

  const int kg = lane >> 4;
  const int lr = lane & 15;

  #pragma unroll 1
  for (int ci = 0; ci < 4; ++ci){
    f32x4 acc[4][2];
    #pragma unroll
    for (int fr = 0; fr < 4; ++fr)
      #pragma unroll
      for (int fc = 0; fc < 2; ++fc) acc[fr][fc] = (f32x4){0.f,0.f,0.f,0.f};

    // panel p = ci*8 + w (32 c-rows); chunk kk = 1024 elems (2 KB)
    const unsigned short* pbase = cbB + ((size_t)(ci*8 + w))*16384;
    const int loff = lr*32 + kg*8;

    s16x8 a[4], b[2][2];
    // ---- prologue: B(0), B(1) ----
    #pragma unroll
    for (int fc = 0; fc < 2; ++fc)
      b[0][fc] = *(const s16x8*)(pbase + 0*1024 + fc*512 + loff);
    #pragma unroll
    for (int fc = 0; fc < 2; ++fc)
      b[1][fc] = *(const s16x8*)(pbase + 1*1024 + fc*512 + loff);

    #pragma unroll
    for (int kk = 0; kk < 16; ++kk){
      if (kk < 15) asm volatile("s_waitcnt vmcnt(2)" ::: "memory");
      else         asm volatile("s_waitcnt vmcnt(0)" ::: "memory");
      __builtin_amdgcn_sched_barrier(0);
      // A fragments for this kk (LDS, single-buffered; TLP covers latency)
      #pragma unroll
      for (int fr = 0; fr < 4; ++fr){
        const int row = fr*16 + lr;
        const int sp  = (kk*4 + kg) ^ (row & 7);
        a[fr] = *(const s16x8*)&sA[row*512 + sp*8];
      }
      __builtin_amdgcn_s_setprio(1);
      #pragma unroll
      for (int fr = 0; fr < 4; ++fr)
        #pragma unroll
        for (int fc = 0; fc < 2; ++fc)
          acc[fr][fc] = __builtin_amdgcn_mfma_f32_16x16x32_bf16(a[fr], b[kk & 1][fc], acc[fr][fc], 0, 0, 0);
      __builtin_amdgcn_s_setprio(0);
      __builtin_amdgcn_sched_barrier(0);
      // B prefetch for kk+2 into b[kk&1] (WAR-safe: cluster kk consumed it)
      if (kk < 14){
        #pragma unroll
        for (int fc = 0; fc < 2; ++fc)
          b[kk & 1][fc] = *(const s16x8*)(pbase + (size_t)(kk+2)*1024 + fc*512 + loff);
      }
    }

    // per-pass epilogue: exp + cw-weight + 16-lane shuffle reduction
    #pragma unroll
    for (int fr = 0; fr < 4; ++fr){
      float es[4] = {0,0,0,0}, ws[4] = {0,0,0,0};
      #pragma unroll
      for (int fc = 0; fc < 2; ++fc){
        const int c = ci*256 + w*32 + fc*16 + lr;
        const float cwv = cwl[c];
        #pragma unroll
        for (int r = 0; r < 4; ++r){
          const float e = __expf(acc[fr][fc][r]);   // scale pre-folded into cb
          es[r] += e;
          ws[r] += e * cwv;
        }
      }
      #pragma unroll
      for (int r = 0; r < 4; ++r){
        float a0 = es[r], b0 = ws[r];
        #pragma unroll
        for (int m = 1; m < 16; m <<= 1){
          a0 += __shfl_xor(a0, m, 64);
          b0 += __shfl_xor(b0, m, 64);
        }
        if (lr == 0){
          const int row = fr*16 + kg*4 + r;   // C/D map: row=(l>>4)*4+reg
          pe[w][row] += a0;
          pw[w][row] += b0;
        }
      }
    }
  }

  __syncthreads();
  if (t < 64){
    float se = 0.f, sw = 0.f;
    #pragma unroll
    for (int i = 0; i < 8; ++i){ se += pe[i][t]; sw += pw[i][t]; }
    ew_out[m0 + t] = sw / se;
  }
}

// ---------------------------------------------------------------------------
// Kernel C: summary[n][d] = sum_s ew[n,s] * V[n,s,d]. grid = n x d-half.
// ---------------------------------------------------------------------------
__global__ __launch_bounds__(256) void k_summary(const float* __restrict__ V,
                                                 const float* __restrict__ ew,
                                                 float* __restrict__ sm){
  __shared__ float e[256];
  __shared__ f32x4 red[3][64];
  const int t = threadIdx.x;
  const int lane = t & 63, w = t >> 6;
  const int n = blockIdx.x >> 1;
  const int d0 = (blockIdx.x & 1) * 256;
  e[t] = ew[(size_t)n*256 + t];
  __syncthreads();
  const float* vb = V + (size_t)n*131072 + d0 + lane*4;
  f32x4 acc = {0.f,0.f,0.f,0.f};
  #pragma unroll 8
  for (int s = w; s < 256; s += 4){
    const f32x4 v = *(const f32x4*)(vb + (size_t)s*512);
    acc += e[s] * v;
  }
  if (w > 0) red[w-1][lane] = acc;
  __syncthreads();
  if (w == 0){
    acc += red[0][lane] + red[1][lane] + red[2][lane];
    *(f32x4*)(sm + (size_t)n*512 + d0 + lane*4) = acc;
  }
}

// ---------------------------------------------------------------------------
// Kernel D: logits = sm@Wc^T + bc ; recon = sm@Wr^T + br.
// grid = 64 n-blocks (8 n) x 4 W-slices (378 rows) = 256 blocks: full CU
// coverage + half the W L2 re-reads vs 128x(4n) version.
// ---------------------------------------------------------------------------
__global__ __launch_bounds__(256) void k_readout(const float* __restrict__ sm,
                                                 const float* __restrict__ Wc,
                                                 const float* __restrict__ bc,
                                                 const float* __restrict__ Wr,
                                                 const float* __restrict__ br,
                                                 float* __restrict__ logits,
                                                 float* __restrict__ recon){
  __shared__ __align__(16) float sl[8][512];
  const int t = threadIdx.x;
  const int nb  = blockIdx.x >> 2;
  const int wsl = blockIdx.x & 3;
  const int n0 = nb * 8;
  #pragma unroll
  for (int j = 0; j < 16; ++j){
    const int o = t + 256*j; const int ni = o >> 9, d = o & 511;
    sl[ni][d] = sm[(size_t)(n0+ni)*512 + d];
  }
  __syncthreads();
  #pragma unroll 1
  for (int j = 0; j < 2; ++j){
    const int rel = t + 256*j;
    if (rel >= 378) continue;
    const int o = wsl*378 + rel;          // 0..1511
    const bool isl = o < 1000;
    const float* wrow = isl ? (Wc + (size_t)o*512) : (Wr + (size_t)(o-1000)*512);
    const float bias  = isl ? bc[o] : br[o-1000];
    const f32x4* w4 = (const f32x4*)wrow;
    f32x4 av[8];
    #pragma unroll
    for (int ni = 0; ni < 8; ++ni) av[ni] = (f32x4){0.f,0.f,0.f,0.f};
    for (int d = 0; d < 128; ++d){
      const f32x4 wv = w4[d];
      #pragma unroll
      for (int ni = 0; ni < 8; ++ni)
        av[ni] += wv * ((const f32x4*)sl[ni])[d];
    }
    #pragma unroll
    for (int ni = 0; ni < 8; ++ni){
      const float r = hsum4(av[ni]) + bias;
      if (isl) logits[(size_t)(n0+ni)*1000 + o] = r;
      else     recon [(size_t)(n0+ni)*512 + (o-1000)] = r;
    }
  }
}

extern "C" void kernel_launch(void* const* d_in, const int* in_sizes, int n_in,
                              void* d_out, int out_size, void* d_ws, size_t ws_size,
                              hipStream_t stream) {
  const float* q  = (const float*)d_in[0];
  const float* K  = (const float*)d_in[1];
  const float* V  = (const float*)d_in[2];
  const float* cb = (const float*)d_in[3];
  const float* Wq = (const float*)d_in[4];
  const float* Wc = (const float*)d_in[5];
  const float* bc = (const float*)d_in[6];
  const float* Wr = (const float*)d_in[7];
  const float* br = (const float*)d_in[8];

  float* out    = (float*)d_out;
  float* logits = out;                         // 512*1000
  float* recon  = out + 512*1000;              // 512*512
  float* ew     = out + 512*1000 + 512*512;    // 512*256

  char* wsb = (char*)d_ws;
  unsigned short* cbB = (unsigned short*)wsb;            // 1 MB
  float* cw = (float*)(wsb + (1u<<20));                  // 2 MB
  float* sm = (float*)(wsb + 3u*(1u<<20));               // 1 MB

  hipLaunchKernelGGL(k_cbarr,   dim3(256),  dim3(256), 0, stream, cb, cbB);
  hipLaunchKernelGGL(k_cw,      dim3(128),  dim3(256), 0, stream, q, Wq, cb, cw);
  hipLaunchKernelGGL(k_scores,  dim3(2048), dim3(512), 0, stream, K, cbB, cw, ew);
  hipLaunchKernelGGL(k_summary, dim3(1024), dim3(256), 0, stream, V, ew, sm);
  hipLaunchKernelGGL(k_readout, dim3(256),  dim3(256), 0, stream, sm, Wc, bc, Wr, br, logits, recon);
}